// Round 1
// baseline (1834.368 us; speedup 1.0000x reference)
//
#include <hip/hip_runtime.h>

#define N_NODES 260000
#define N_EDGES 8320000
#define IN_DIM 4
#define H1 26
#define H2 11
#define GRAPH_NODES 26
#define N_GRAPHS 10000

// ---------------- kernel 1: agg1[i] = W1 x_i + b1  (self-loop init) ----------------
__global__ void init1_kernel(const float* __restrict__ x, const float* __restrict__ W1,
                             const float* __restrict__ b1, float* __restrict__ agg1) {
    int i = blockIdx.x * blockDim.x + threadIdx.x;
    if (i >= N_NODES) return;
    float4 xv = ((const float4*)x)[i];
    #pragma unroll
    for (int j = 0; j < H1; ++j) {
        float v = b1[j] + xv.x * W1[j*4+0] + xv.y * W1[j*4+1]
                        + xv.z * W1[j*4+2] + xv.w * W1[j*4+3];
        agg1[i*H1 + j] = v;
    }
}

// ------------- kernel 2: scatter layer 1, message recomputed from x -------------
// 32 lanes per edge; lane ch (<26) computes message channel ch and atomically adds.
__global__ void scatter1_kernel(const int* __restrict__ row, const int* __restrict__ col,
                                const float* __restrict__ x,
                                const float* __restrict__ W1, const float* __restrict__ b1,
                                float* __restrict__ agg1) {
    int tid = blockIdx.x * blockDim.x + threadIdx.x;
    int ch = tid & 31;
    int group = tid >> 5;
    int nGroups = (gridDim.x * blockDim.x) >> 5;
    if (ch >= H1) return;
    float w0 = W1[ch*4+0], w1 = W1[ch*4+1], w2 = W1[ch*4+2], w3 = W1[ch*4+3];
    float bb = b1[ch];
    for (int e = group; e < N_EDGES; e += nGroups) {
        int r = row[e];
        int c = col[e];
        float4 xv = ((const float4*)x)[r];
        float m = bb + xv.x*w0 + xv.y*w1 + xv.z*w2 + xv.w*w3;
        atomicAdd(&agg1[c*H1 + ch], m);
    }
}

// ------- kernel 3: h1 = tanh(agg1); z2 = W2 h1 + b2; agg2 = z2 (self-loop) -------
__global__ void layer2_kernel(const float* __restrict__ agg1,
                              const float* __restrict__ W2, const float* __restrict__ b2,
                              float* __restrict__ z2, float* __restrict__ agg2) {
    __shared__ float sW[H2*H1];
    __shared__ float sb[H2];
    for (int t = threadIdx.x; t < H2*H1; t += blockDim.x) sW[t] = W2[t];
    if (threadIdx.x < H2) sb[threadIdx.x] = b2[threadIdx.x];
    __syncthreads();
    int i = blockIdx.x * blockDim.x + threadIdx.x;
    if (i >= N_NODES) return;
    float h[H1];
    #pragma unroll
    for (int k = 0; k < H1; ++k) h[k] = tanhf(agg1[i*H1 + k]);
    #pragma unroll
    for (int j = 0; j < H2; ++j) {
        float v = sb[j];
        #pragma unroll
        for (int k = 0; k < H1; ++k) v += h[k] * sW[j*H1 + k];
        z2[i*H2 + j] = v;
        agg2[i*H2 + j] = v;
    }
}

// ---------------- kernel 4: scatter layer 2 (gather z2, 16 lanes/edge) ----------------
__global__ void scatter2_kernel(const int* __restrict__ row, const int* __restrict__ col,
                                const float* __restrict__ z2, float* __restrict__ agg2) {
    int tid = blockIdx.x * blockDim.x + threadIdx.x;
    int ch = tid & 15;
    int group = tid >> 4;
    int nGroups = (gridDim.x * blockDim.x) >> 4;
    if (ch >= H2) return;
    for (int e = group; e < N_EDGES; e += nGroups) {
        int r = row[e];
        int c = col[e];
        atomicAdd(&agg2[c*H2 + ch], z2[r*H2 + ch]);
    }
}

// ------- kernel 5: tanh+maxpool -> per-graph sum (26 nodes) -> linear -> softmax -------
// 32 lanes per graph; lanes 0..25 handle one node each.
__global__ void final_kernel(const float* __restrict__ agg2,
                             const float* __restrict__ Wl, const float* __restrict__ bl,
                             float* __restrict__ out) {
    int tid = blockIdx.x * blockDim.x + threadIdx.x;
    int lane = tid & 31;
    int g = tid >> 5;
    if (g >= N_GRAPHS) return;
    float p0 = 0.f, p1 = 0.f, p2 = 0.f, p3 = 0.f;
    if (lane < GRAPH_NODES) {
        const float* h = agg2 + (g*GRAPH_NODES + lane)*H2;
        // MaxPool1d(3, stride 3, pad 1) over 11 channels; tanh after max (monotone).
        p0 = tanhf(fmaxf(h[0], h[1]));
        p1 = tanhf(fmaxf(fmaxf(h[2], h[3]), h[4]));
        p2 = tanhf(fmaxf(fmaxf(h[5], h[6]), h[7]));
        p3 = tanhf(fmaxf(fmaxf(h[8], h[9]), h[10]));
    }
    #pragma unroll
    for (int off = 16; off > 0; off >>= 1) {
        p0 += __shfl_down(p0, off, 32);
        p1 += __shfl_down(p1, off, 32);
        p2 += __shfl_down(p2, off, 32);
        p3 += __shfl_down(p3, off, 32);
    }
    if (lane == 0) {
        float o0 = bl[0] + p0*Wl[0] + p1*Wl[1] + p2*Wl[2] + p3*Wl[3];
        float o1 = bl[1] + p0*Wl[4] + p1*Wl[5] + p2*Wl[6] + p3*Wl[7];
        float m = fmaxf(o0, o1);
        float e0 = expf(o0 - m), e1 = expf(o1 - m);
        float s = e0 + e1;
        out[g*2 + 0] = e0 / s;
        out[g*2 + 1] = e1 / s;
    }
}

extern "C" void kernel_launch(void* const* d_in, const int* in_sizes, int n_in,
                              void* d_out, int out_size, void* d_ws, size_t ws_size,
                              hipStream_t stream) {
    const float* x  = (const float*)d_in[0];
    const int* ei   = (const int*)d_in[1];
    const float* W1 = (const float*)d_in[2];
    const float* b1 = (const float*)d_in[3];
    const float* W2 = (const float*)d_in[4];
    const float* b2 = (const float*)d_in[5];
    const float* Wl = (const float*)d_in[6];
    const float* bl = (const float*)d_in[7];
    float* out = (float*)d_out;

    const int* row = ei;            // edge_index[0]
    const int* col = ei + N_EDGES;  // edge_index[1]

    // workspace layout (floats):
    //   agg1: [0, 6,760,000)            26 ch
    //   z2:   [6,760,000, 9,620,000)    11 ch
    //   agg2: [9,620,000, 12,480,000)   11 ch   -> 49.9 MB total
    float* ws  = (float*)d_ws;
    float* agg1 = ws;
    float* z2   = ws + (size_t)N_NODES * H1;
    float* agg2 = z2 + (size_t)N_NODES * H2;

    dim3 blk(256);
    int nodeBlocks = (N_NODES + 255) / 256;

    init1_kernel<<<nodeBlocks, blk, 0, stream>>>(x, W1, b1, agg1);
    scatter1_kernel<<<4096, blk, 0, stream>>>(row, col, x, W1, b1, agg1);
    layer2_kernel<<<nodeBlocks, blk, 0, stream>>>(agg1, W2, b2, z2, agg2);
    scatter2_kernel<<<4096, blk, 0, stream>>>(row, col, z2, agg2);
    final_kernel<<<(N_GRAPHS*32 + 255)/256, blk, 0, stream>>>(agg2, Wl, bl, out);
}